// Round 1
// baseline (511.383 us; speedup 1.0000x reference)
//
#include <hip/hip_runtime.h>

typedef __attribute__((ext_vector_type(8))) short short8;
typedef __attribute__((ext_vector_type(4))) float f32x4;

#define L2E 1.44269504088896340736f

__device__ __forceinline__ unsigned short f2bf(float x) {
    union { float f; unsigned int u; } v; v.f = x;
    unsigned int u = v.u;
    unsigned int r = (u + 0x7FFFu + ((u >> 16) & 1u)) >> 16;
    return (unsigned short)r;
}

// exp(mish(x)) :  mish(x) = x * t/(t+2),  t = u*(u+2),  u = e^x
__device__ __forceinline__ float expw(float x) {
    float u = __builtin_amdgcn_exp2f(x * L2E);
    float t = u * (u + 2.0f);
    float m = x * t * __builtin_amdgcn_rcpf(t + 2.0f);
    return __builtin_amdgcn_exp2f(m * L2E);
}

__device__ __forceinline__ float mishf(float x) {
    float u = __builtin_amdgcn_exp2f(x * L2E);
    float t = u * (u + 2.0f);
    return x * t * __builtin_amdgcn_rcpf(t + 2.0f);
}

// ---------------- kernel: W (512x256 f32) -> WT bf16 (256x512) ----------------
__global__ void k_cvt_wt(const float* __restrict__ W, unsigned short* __restrict__ wt) {
    int c = blockIdx.x;           // 0..255 output row (col of W)
    int t = threadIdx.x;          // 0..255
    wt[c * 512 + t]       = f2bf(W[(size_t)t * 256 + c]);
    wt[c * 512 + t + 256] = f2bf(W[(size_t)(t + 256) * 256 + c]);
}

// ---------------- kernel: h = input @ W  (bf16 MFMA, fp32 accum) --------------
// grid 256 blocks, 128 threads (2 waves x 16 rows). Writes h fp32 and hbT bf16.
__global__ __launch_bounds__(128) void k_gemm_h(const float* __restrict__ input,
                                                const unsigned short* __restrict__ wt,
                                                float* __restrict__ h,
                                                unsigned short* __restrict__ hbt) {
    int tid = threadIdx.x;
    int w = tid >> 6, lane = tid & 63, g = lane >> 4, r = lane & 15;
    int base = blockIdx.x * 32 + w * 16;

    f32x4 acc[16];
#pragma unroll
    for (int n = 0; n < 16; ++n) acc[n] = (f32x4)0.0f;

    const float* arow = input + (size_t)(base + r) * 512 + g * 8;
    for (int kb = 0; kb < 512; kb += 32) {
        float4 a0 = *(const float4*)(arow + kb);
        float4 a1 = *(const float4*)(arow + kb + 4);
        short8 af;
        af[0] = (short)f2bf(a0.x); af[1] = (short)f2bf(a0.y);
        af[2] = (short)f2bf(a0.z); af[3] = (short)f2bf(a0.w);
        af[4] = (short)f2bf(a1.x); af[5] = (short)f2bf(a1.y);
        af[6] = (short)f2bf(a1.z); af[7] = (short)f2bf(a1.w);
#pragma unroll
        for (int n = 0; n < 16; ++n) {
            short8 bf = *(const short8*)(wt + (size_t)(n * 16 + r) * 512 + kb + g * 8);
            acc[n] = __builtin_amdgcn_mfma_f32_16x16x32_bf16(af, bf, acc[n], 0, 0, 0);
        }
    }
    int rowc = base + g * 4;
#pragma unroll
    for (int n = 0; n < 16; ++n) {
        int col = n * 16 + r;
#pragma unroll
        for (int i = 0; i < 4; ++i)
            h[(size_t)(rowc + i) * 256 + col] = acc[n][i];
        ushort4 pk;
        pk.x = f2bf(acc[n][0]); pk.y = f2bf(acc[n][1]);
        pk.z = f2bf(acc[n][2]); pk.w = f2bf(acc[n][3]);
        *(ushort4*)(hbt + (size_t)col * 8192 + rowc) = pk;
    }
}

// ---------------- kernel: s1 = h@a1, s2 = h@a2 (one wave per row) -------------
__global__ void k_s1s2(const float* __restrict__ h, const float* __restrict__ a,
                       float* __restrict__ s1, float* __restrict__ s2) {
    int lane = threadIdx.x & 63;
    int i = blockIdx.x * 4 + (threadIdx.x >> 6);
    const float* hr = h + (size_t)i * 256;
    float p1 = 0.f, p2 = 0.f;
#pragma unroll
    for (int q = 0; q < 4; ++q) {
        int f = lane + q * 64;
        float hv = hr[f];
        p1 += hv * a[f];
        p2 += hv * a[256 + f];
    }
#pragma unroll
    for (int off = 32; off >= 1; off >>= 1) {
        p1 += __shfl_xor(p1, off);
        p2 += __shfl_xor(p2, off);
    }
    if (lane == 0) { s1[i] = p1; s2[i] = p2; }
}

// ---------------- main kernel: masked-softmax-weighted PV via MFMA ------------
// grid (64 row-blocks, 4 K-chunks), 512 threads = 8 waves x 16 rows (BM=128).
// Per K-step 32: generate P A-frag in regs, MFMA vs LDS-staged hbT tile,
// extra ones-column MFMA accumulates Z. Writes partial S,Z per chunk.
__global__ __launch_bounds__(512, 1) void k_attn(const float* __restrict__ adj,
                                                 const unsigned short* __restrict__ hbt,
                                                 const float* __restrict__ s1,
                                                 const float* __restrict__ s2,
                                                 float* __restrict__ pS,
                                                 float* __restrict__ pZ) {
    __shared__ __align__(16) unsigned short tile[2][8192]; // 2 x (256 rows x 32 k) bf16

    int tid = threadIdx.x;
    int w = tid >> 6, lane = tid & 63, g = lane >> 4, r = lane & 15;
    int mb = blockIdx.x, chunk = blockIdx.y;
    int rowA = mb * 128 + w * 16 + r;
    const float* adjrow = adj + (size_t)rowA * 8192;
    float s1v = s1[rowA];

    // staging mapping (thread t loads 2 of 1024 16B chunks; XOR-swizzled slots)
    int c0 = tid, c1 = tid + 512;
    int row0 = c0 >> 2, sl0 = c0 & 3;
    int row1 = c1 >> 2, sl1 = c1 & 3;
    int ss0 = sl0 ^ ((row0 >> 1) & 3);
    int ss1 = sl1 ^ ((row1 >> 1) & 3);
    const unsigned short* hp0 = hbt + (size_t)row0 * 8192 + ss0 * 8;
    const unsigned short* hp1 = hbt + (size_t)row1 * 8192 + ss1 * 8;
    int ld0 = row0 * 32 + sl0 * 8, ld1 = row1 * 32 + sl1 * 8;
    int kc = chunk * 2048;
    int sw = (r >> 1) & 3;
    int boff = r * 32 + ((g ^ sw) * 8);
    const float* s2g = s2 + g * 8;

    f32x4 acc[17];
#pragma unroll
    for (int n = 0; n < 17; ++n) acc[n] = (f32x4)0.0f;

    short8 onef;
    {
        short ov = (r == 0) ? (short)0x3F80 : (short)0;
#pragma unroll
        for (int j = 0; j < 8; ++j) onef[j] = ov;
    }

    // prologue: stage step 0, load adj/s2 regs for step 0
    {
        uint4 st0 = *(const uint4*)(hp0 + kc);
        uint4 st1 = *(const uint4*)(hp1 + kc);
        *(uint4*)&tile[0][ld0] = st0;
        *(uint4*)&tile[0][ld1] = st1;
    }
    float4 aj0 = *(const float4*)(adjrow + kc + g * 8);
    float4 aj1 = *(const float4*)(adjrow + kc + g * 8 + 4);
    float4 sv0 = *(const float4*)(s2g + kc);
    float4 sv1 = *(const float4*)(s2g + kc + 4);
    __syncthreads();

    for (int s = 0; s < 64; ++s) {
        int b = s & 1;
        // prefetch next step (clamped address on last iter; values unused then)
        int kn = kc + ((s < 63) ? (s + 1) * 32 : 0);
        uint4 nt0 = *(const uint4*)(hp0 + kn);
        uint4 nt1 = *(const uint4*)(hp1 + kn);
        float4 na0 = *(const float4*)(adjrow + kn + g * 8);
        float4 na1 = *(const float4*)(adjrow + kn + g * 8 + 4);
        float4 nv0 = *(const float4*)(s2g + kn);
        float4 nv1 = *(const float4*)(s2g + kn + 4);

        // generate P fragment: p = adj * exp(mish(s1+s2)), bf16
        short8 af;
        af[0] = (short)f2bf(aj0.x * expw(s1v + sv0.x));
        af[1] = (short)f2bf(aj0.y * expw(s1v + sv0.y));
        af[2] = (short)f2bf(aj0.z * expw(s1v + sv0.z));
        af[3] = (short)f2bf(aj0.w * expw(s1v + sv0.w));
        af[4] = (short)f2bf(aj1.x * expw(s1v + sv1.x));
        af[5] = (short)f2bf(aj1.y * expw(s1v + sv1.y));
        af[6] = (short)f2bf(aj1.z * expw(s1v + sv1.z));
        af[7] = (short)f2bf(aj1.w * expw(s1v + sv1.w));

        const unsigned short* tb = &tile[b][boff];
#pragma unroll
        for (int n = 0; n < 16; ++n) {
            short8 bf = *(const short8*)(tb + n * 512);
            acc[n] = __builtin_amdgcn_mfma_f32_16x16x32_bf16(af, bf, acc[n], 0, 0, 0);
        }
        acc[16] = __builtin_amdgcn_mfma_f32_16x16x32_bf16(af, onef, acc[16], 0, 0, 0);

        __syncthreads();
        *(uint4*)&tile[b ^ 1][ld0] = nt0;
        *(uint4*)&tile[b ^ 1][ld1] = nt1;
        aj0 = na0; aj1 = na1; sv0 = nv0; sv1 = nv1;
        __syncthreads();
    }

    // epilogue: write partial S and Z
    float* ps = pS + ((size_t)chunk << 21);
    int rowc = mb * 128 + w * 16 + g * 4;
#pragma unroll
    for (int n = 0; n < 16; ++n) {
#pragma unroll
        for (int i = 0; i < 4; ++i)
            ps[(size_t)(rowc + i) * 256 + n * 16 + r] = acc[n][i];
    }
    if (r == 0) {
        float* pz = pZ + chunk * 8192 + rowc;
#pragma unroll
        for (int i = 0; i < 4; ++i) pz[i] = acc[16][i];
    }
}

// ---------------- final: reduce partials, divide, mish ------------------------
__global__ void k_final(const float* __restrict__ pS, const float* __restrict__ pZ,
                        float* __restrict__ out) {
    int i = blockIdx.x;
    int f = threadIdx.x;
    size_t o = (size_t)i * 256 + f;
    float sv = pS[o] + pS[o + (1u << 21)] + pS[o + (2u << 21)] + pS[o + (3u << 21)];
    float z = pZ[i] + pZ[i + 8192] + pZ[i + 16384] + pZ[i + 24576];
    float hp = sv / z;
    out[o] = mishf(hp);
}

extern "C" void kernel_launch(void* const* d_in, const int* in_sizes, int n_in,
                              void* d_out, int out_size, void* d_ws, size_t ws_size,
                              hipStream_t stream) {
    const float* input = (const float*)d_in[0];
    const float* adj   = (const float*)d_in[1];
    const float* W     = (const float*)d_in[2];
    const float* a     = (const float*)d_in[3];
    float* out = (float*)d_out;

    char* ws = (char*)d_ws;
    unsigned short* wt  = (unsigned short*)ws;                 // 256 KB
    float*  h   = (float*)(ws + 262144);                       // 8 MB
    unsigned short* hbt = (unsigned short*)(ws + 8650752);     // 4 MB
    float*  s1  = (float*)(ws + 12845056);                     // 32 KB
    float*  s2  = (float*)(ws + 12877824);                     // 32 KB
    float*  pS  = (float*)(ws + 12910592);                     // 32 MB (4 x 8192 x 256)
    float*  pZ  = (float*)(ws + 46465024);                     // 128 KB  (end ~46.6 MB)

    hipLaunchKernelGGL(k_cvt_wt, dim3(256), dim3(256), 0, stream, W, wt);
    hipLaunchKernelGGL(k_gemm_h, dim3(256), dim3(128), 0, stream, input, wt, h, hbt);
    hipLaunchKernelGGL(k_s1s2, dim3(2048), dim3(256), 0, stream, h, a, s1, s2);
    hipLaunchKernelGGL(k_attn, dim3(64, 4), dim3(512), 0, stream, adj, hbt, s1, s2, pS, pZ);
    hipLaunchKernelGGL(k_final, dim3(8192), dim3(256), 0, stream, pS, pZ, out);
}

// Round 2
// 460.072 us; speedup vs baseline: 1.1115x; 1.1115x over previous
//
#include <hip/hip_runtime.h>

typedef __attribute__((ext_vector_type(8))) short short8;
typedef __attribute__((ext_vector_type(4))) float f32x4;

#define L2E 1.44269504088896340736f

__device__ __forceinline__ unsigned short f2bf(float x) {
    union { float f; unsigned int u; } v; v.f = x;
    unsigned int u = v.u;
    unsigned int r = (u + 0x7FFFu + ((u >> 16) & 1u)) >> 16;
    return (unsigned short)r;
}

__device__ __forceinline__ float mishf(float x) {
    float u = __builtin_amdgcn_exp2f(x * L2E);
    float t = u * (u + 2.0f);
    return x * t * __builtin_amdgcn_rcpf(t + 2.0f);
}

// p = adj * exp(mish(s1+s2)) computed in log2-domain: xL = (s1+s2)*L2E (pre-scaled),
// u = e^{s1}*e^{s2} from precomputed factors. bf16 via round-half-up (cheap).
__device__ __forceinline__ short pw(float aj, float sv, float ev, float s1Lv, float e1v) {
    float xL = s1Lv + sv;
    float u  = e1v * ev;
    float t  = u * (u + 2.0f);
    float m  = xL * t * __builtin_amdgcn_rcpf(t + 2.0f);
    float p  = aj * __builtin_amdgcn_exp2f(m);
    union { float f; unsigned int u; } b; b.f = p;
    return (short)((b.u + 0x8000u) >> 16);
}

typedef __attribute__((address_space(1))) const unsigned int guint;
typedef __attribute__((address_space(3))) unsigned int luint;
__device__ __forceinline__ void lds16(const void* g, void* l) {
    __builtin_amdgcn_global_load_lds((guint*)g, (luint*)l, 16, 0, 0);
}

// ---------------- kernel: W (512x256 f32) -> WT bf16 (256x512) ----------------
__global__ void k_cvt_wt(const float* __restrict__ W, unsigned short* __restrict__ wt) {
    int c = blockIdx.x;
    int t = threadIdx.x;
    wt[c * 512 + t]       = f2bf(W[(size_t)t * 256 + c]);
    wt[c * 512 + t + 256] = f2bf(W[(size_t)(t + 256) * 256 + c]);
}

// ------- h = input @ W (bf16 MFMA) fused with s1/s2 epilogue ------------------
// 512 blocks x 64 threads (1 wave, 16 rows). Writes hbt (bf16 h^T), s1L, s2L, e2.
__global__ __launch_bounds__(64) void k_gemm_h(const float* __restrict__ input,
                                               const unsigned short* __restrict__ wt,
                                               const float* __restrict__ a,
                                               unsigned short* __restrict__ hbt,
                                               float* __restrict__ s1L,
                                               float* __restrict__ s2L,
                                               float* __restrict__ e2) {
    int lane = threadIdx.x & 63, g = lane >> 4, r = lane & 15;
    int base = blockIdx.x * 16;

    f32x4 acc[16];
#pragma unroll
    for (int n = 0; n < 16; ++n) acc[n] = (f32x4)0.0f;

    const float* arow = input + (size_t)(base + r) * 512 + g * 8;
#pragma unroll 2
    for (int kb = 0; kb < 512; kb += 32) {
        float4 a0 = *(const float4*)(arow + kb);
        float4 a1 = *(const float4*)(arow + kb + 4);
        short8 af;
        af[0] = (short)f2bf(a0.x); af[1] = (short)f2bf(a0.y);
        af[2] = (short)f2bf(a0.z); af[3] = (short)f2bf(a0.w);
        af[4] = (short)f2bf(a1.x); af[5] = (short)f2bf(a1.y);
        af[6] = (short)f2bf(a1.z); af[7] = (short)f2bf(a1.w);
#pragma unroll
        for (int n = 0; n < 16; ++n) {
            short8 bf = *(const short8*)(wt + (size_t)(n * 16 + r) * 512 + kb + g * 8);
            acc[n] = __builtin_amdgcn_mfma_f32_16x16x32_bf16(af, bf, acc[n], 0, 0, 0);
        }
    }
    int rowc = base + g * 4;
#pragma unroll
    for (int n = 0; n < 16; ++n) {
        int col = n * 16 + r;
        ushort4 pk;
        pk.x = f2bf(acc[n][0]); pk.y = f2bf(acc[n][1]);
        pk.z = f2bf(acc[n][2]); pk.w = f2bf(acc[n][3]);
        *(ushort4*)(hbt + (size_t)col * 8192 + rowc) = pk;
    }
    // s1/s2: per-lane partials over n, reduce across r (xor 1,2,4,8)
    float p1[4] = {0,0,0,0}, p2[4] = {0,0,0,0};
#pragma unroll
    for (int n = 0; n < 16; ++n) {
        float a1v = a[n * 16 + r];
        float a2v = a[256 + n * 16 + r];
#pragma unroll
        for (int i = 0; i < 4; ++i) {
            p1[i] += acc[n][i] * a1v;
            p2[i] += acc[n][i] * a2v;
        }
    }
#pragma unroll
    for (int off = 8; off >= 1; off >>= 1) {
#pragma unroll
        for (int i = 0; i < 4; ++i) {
            p1[i] += __shfl_xor(p1[i], off);
            p2[i] += __shfl_xor(p2[i], off);
        }
    }
    if (r == 0) {
#pragma unroll
        for (int i = 0; i < 4; ++i) {
            int row = rowc + i;
            s1L[row] = p1[i] * L2E;
            float s2l = p2[i] * L2E;
            s2L[row] = s2l;
            e2[row] = __builtin_amdgcn_exp2f(s2l);
        }
    }
}

// ---------------- main kernel: pipelined masked-softmax PV --------------------
// grid (128 row-blocks, 4 K-chunks), 256 threads = 4 waves x 16 rows (BM=64).
// Triple-buffered LDS, ONE raw s_barrier per 32-k step, counted vmcnt(10).
__global__ __launch_bounds__(256, 2) void k_attn(const float* __restrict__ adj,
                                                 const unsigned short* __restrict__ hbt,
                                                 const float* __restrict__ s1L,
                                                 const float* __restrict__ s2L,
                                                 const float* __restrict__ e2,
                                                 float* __restrict__ pS,
                                                 float* __restrict__ pZ) {
    __shared__ __align__(16) unsigned short tile[3][8192]; // 3 x (256 rows x 32 k) bf16

    int tid = threadIdx.x;
    int w = tid >> 6, lane = tid & 63, g = lane >> 4, r = lane & 15;
    int mb = blockIdx.x, chunk = blockIdx.y;
    int kc = chunk * 2048;
    int rowA = mb * 64 + w * 16 + r;
    float s1Lv = s1L[rowA];
    float e1v = __builtin_amdgcn_exp2f(s1Lv);

    const float* adjp = adj + (size_t)rowA * 8192 + kc + g * 8;
    const float* svp  = s2L + kc + g * 8;
    const float* evp  = e2  + kc + g * 8;

    // staging: wave w, instr j, lane l -> chunk c = 256w+64j+l; row=c>>2, slot=l&3
    // global source pre-swizzled (slot ^ ((row>>1)&3)); LDS dest linear (rule 21)
    const unsigned short *hsrc0, *hsrc1, *hsrc2, *hsrc3;
    {
        int l2 = lane >> 2, sl = lane & 3;
        int r0 = 64 * w + l2,      ss0 = sl ^ ((r0 >> 1) & 3);
        int r1 = 64 * w + 16 + l2, ss1 = sl ^ ((r1 >> 1) & 3);
        int r2 = 64 * w + 32 + l2, ss2 = sl ^ ((r2 >> 1) & 3);
        int r3 = 64 * w + 48 + l2, ss3 = sl ^ ((r3 >> 1) & 3);
        hsrc0 = hbt + (size_t)r0 * 8192 + kc + ss0 * 8;
        hsrc1 = hbt + (size_t)r1 * 8192 + kc + ss1 * 8;
        hsrc2 = hbt + (size_t)r2 * 8192 + kc + ss2 * 8;
        hsrc3 = hbt + (size_t)r3 * 8192 + kc + ss3 * 8;
    }
    char* ldsbase = (char*)&tile[0][0] + w * 4096;
    int sw = (r >> 1) & 3;
    int rdoff = r * 64 + ((g ^ sw) * 16);

    f32x4 acc[17];
#pragma unroll
    for (int n = 0; n < 17; ++n) acc[n] = (f32x4)0.0f;

    short8 onef;
    {
        short ov = (r == 0) ? (short)0x3F80 : (short)0;
#pragma unroll
        for (int j = 0; j < 8; ++j) onef[j] = ov;
    }

    float4 ajA0, ajA1, svA0, svA1, evA0, evA1;
    float4 ajB0, ajB1, svB0, svB1, evB0, evB1;

#define ISSUE(tt, bufn, AJ0, AJ1, SV0, SV1, EV0, EV1) do {                     \
        int t_ = (tt); if (t_ > 63) t_ = 63;                                   \
        int ko_ = t_ * 32;                                                     \
        char* lb_ = ldsbase + (bufn) * 16384;                                  \
        lds16(hsrc0 + ko_, lb_);                                               \
        lds16(hsrc1 + ko_, lb_ + 1024);                                        \
        lds16(hsrc2 + ko_, lb_ + 2048);                                        \
        lds16(hsrc3 + ko_, lb_ + 3072);                                        \
        AJ0 = *(const float4*)(adjp + ko_);                                    \
        AJ1 = *(const float4*)(adjp + ko_ + 4);                                \
        SV0 = *(const float4*)(svp + ko_);                                     \
        SV1 = *(const float4*)(svp + ko_ + 4);                                 \
        EV0 = *(const float4*)(evp + ko_);                                     \
        EV1 = *(const float4*)(evp + ko_ + 4);                                 \
    } while (0)

#define WAITBAR() do {                                                         \
        asm volatile("s_waitcnt vmcnt(10)" ::: "memory");                      \
        __builtin_amdgcn_sched_barrier(0);                                     \
        __builtin_amdgcn_s_barrier();                                          \
        __builtin_amdgcn_sched_barrier(0);                                     \
    } while (0)

#define COMPUTE(bufc, AJ0, AJ1, SV0, SV1, EV0, EV1) do {                       \
        short8 af_;                                                            \
        af_[0] = pw(AJ0.x, SV0.x, EV0.x, s1Lv, e1v);                           \
        af_[1] = pw(AJ0.y, SV0.y, EV0.y, s1Lv, e1v);                           \
        af_[2] = pw(AJ0.z, SV0.z, EV0.z, s1Lv, e1v);                           \
        af_[3] = pw(AJ0.w, SV0.w, EV0.w, s1Lv, e1v);                           \
        af_[4] = pw(AJ1.x, SV1.x, EV1.x, s1Lv, e1v);                           \
        af_[5] = pw(AJ1.y, SV1.y, EV1.y, s1Lv, e1v);                           \
        af_[6] = pw(AJ1.z, SV1.z, EV1.z, s1Lv, e1v);                           \
        af_[7] = pw(AJ1.w, SV1.w, EV1.w, s1Lv, e1v);                           \
        const char* tb_ = (const char*)&tile[0][0] + (bufc) * 16384 + rdoff;   \
        _Pragma("unroll")                                                      \
        for (int n_ = 0; n_ < 16; ++n_) {                                      \
            short8 bf_ = *(const short8*)(tb_ + n_ * 1024);                    \
            acc[n_] = __builtin_amdgcn_mfma_f32_16x16x32_bf16(af_, bf_, acc[n_], 0, 0, 0); \
        }                                                                      \
        acc[16] = __builtin_amdgcn_mfma_f32_16x16x32_bf16(af_, onef, acc[16], 0, 0, 0);    \
    } while (0)

    // prologue: stage step 0 into buf0, regs A
    ISSUE(0, 0, ajA0, ajA1, svA0, svA1, evA0, evA1);

    int cur = 0;
    for (int s = 0; s < 64; s += 2) {
        int nb = cur + 1; if (nb == 3) nb = 0;
        ISSUE(s + 1, nb, ajB0, ajB1, svB0, svB1, evB0, evB1);
        WAITBAR();
        COMPUTE(cur, ajA0, ajA1, svA0, svA1, evA0, evA1);
        cur = nb; nb = cur + 1; if (nb == 3) nb = 0;
        ISSUE(s + 2, nb, ajA0, ajA1, svA0, svA1, evA0, evA1);
        WAITBAR();
        COMPUTE(cur, ajB0, ajB1, svB0, svB1, evB0, evB1);
        cur = nb;
    }

    // epilogue: write partial S and Z
    float* ps = pS + ((size_t)chunk << 21);
    int rowc = mb * 64 + w * 16 + g * 4;
#pragma unroll
    for (int n = 0; n < 16; ++n) {
#pragma unroll
        for (int i = 0; i < 4; ++i)
            ps[(size_t)(rowc + i) * 256 + n * 16 + r] = acc[n][i];
    }
    if (r == 0) {
        float* pz = pZ + chunk * 8192 + rowc;
#pragma unroll
        for (int i = 0; i < 4; ++i) pz[i] = acc[16][i];
    }
#undef ISSUE
#undef WAITBAR
#undef COMPUTE
}

// ---------------- final: reduce partials, divide, mish ------------------------
__global__ void k_final(const float* __restrict__ pS, const float* __restrict__ pZ,
                        float* __restrict__ out) {
    int i = blockIdx.x;
    int f = threadIdx.x;
    size_t o = (size_t)i * 256 + f;
    float sv = pS[o] + pS[o + (1u << 21)] + pS[o + (2u << 21)] + pS[o + (3u << 21)];
    float z = pZ[i] + pZ[i + 8192] + pZ[i + 16384] + pZ[i + 24576];
    float hp = sv / z;
    out[o] = mishf(hp);
}

extern "C" void kernel_launch(void* const* d_in, const int* in_sizes, int n_in,
                              void* d_out, int out_size, void* d_ws, size_t ws_size,
                              hipStream_t stream) {
    const float* input = (const float*)d_in[0];
    const float* adj   = (const float*)d_in[1];
    const float* W     = (const float*)d_in[2];
    const float* a     = (const float*)d_in[3];
    float* out = (float*)d_out;

    char* ws = (char*)d_ws;
    unsigned short* wt  = (unsigned short*)ws;                 // 256 KB
    unsigned short* hbt = (unsigned short*)(ws + 262144);      // 4 MB
    float* s1L = (float*)(ws + 4456448);                       // 32 KB
    float* s2L = (float*)(ws + 4489216);                       // 32 KB
    float* e2  = (float*)(ws + 4521984);                       // 32 KB
    float* pS  = (float*)(ws + 4554752);                       // 32 MB
    float* pZ  = (float*)(ws + 38109184);                      // 128 KB (end ~38.2 MB)

    hipLaunchKernelGGL(k_cvt_wt, dim3(256), dim3(256), 0, stream, W, wt);
    hipLaunchKernelGGL(k_gemm_h, dim3(512), dim3(64), 0, stream, input, wt, a, hbt, s1L, s2L, e2);
    hipLaunchKernelGGL(k_attn, dim3(128, 4), dim3(256), 0, stream, adj, hbt, s1L, s2L, e2, pS, pZ);
    hipLaunchKernelGGL(k_final, dim3(8192), dim3(256), 0, stream, pS, pZ, out);
}